// Round 1
// baseline (155.091 us; speedup 1.0000x reference)
//
#include <hip/hip_runtime.h>
#include <math.h>

// ---------------------------------------------------------------------------
// Mann eddy-lifetime: tau = gamma * t^{-2/3} / sqrt(2F1(1/3,17/6,4/3,-t^-2))
// with t = L*||k||. Via Pfaff transform, 2F1 = (t^2 w)^{1/3} * s(w),
// w = 1/(1+t^2), s(w) = sum C_n w^n. Algebra collapses the output to
//   tau = rsqrt( t^2 * cbrt(w) * s(w) )
// Series coefficients C_n decay ~0.2*n^{-3.5}; N=64 terms gives relative
// truncation ~4e-6, far inside the 2% absmax threshold.
// ---------------------------------------------------------------------------

constexpr int NT = 64;

struct CoefArr { float v[NT]; };

constexpr CoefArr gen_coefs() {
    CoefArr r{};
    double term = 1.0;
    r.v[0] = 1.0f;
    for (int n = 0; n + 1 < NT; ++n) {
        const double a  = 1.0 / 3.0;
        const double bp = -1.5;        // c - b = 4/3 - 17/6
        const double c  = 4.0 / 3.0;
        term *= ((a + n) * (bp + n)) / ((c + n) * (n + 1.0));
        r.v[n + 1] = (float)term;
    }
    return r;
}

constexpr CoefArr COEF = gen_coefs();   // folded to immediates at compile time

__device__ __forceinline__ float mann_tau(float t2, float L_unused) {
    // w in (0,1]; t2 == 0 handled by caller (masked to 0)
    float w = 1.0f / (1.0f + t2);
    // Horner over compile-time constants
    float s = COEF.v[NT - 1];
#pragma unroll
    for (int n = NT - 2; n >= 0; --n) s = fmaf(s, w, COEF.v[n]);
    // cbrt(w) via hw log2/exp2 (w > 0 always)
    float cw = exp2f(log2f(w) * (1.0f / 3.0f));
    return rsqrtf(t2 * cw * s);
}

__global__ __launch_bounds__(256) void mann_elt_kernel(
    const float* __restrict__ k,
    const float* __restrict__ Lp,
    const float* __restrict__ gp,
    float* __restrict__ out,
    int n)               // n = number of output elements
{
    const int gid  = blockIdx.x * blockDim.x + threadIdx.x;
    const int base = gid * 4;
    if (base >= n) return;

    const float L  = Lp[0];
    const float g  = gp[0];
    const float L2 = L * L;

    if (base + 3 < n || (n & 3) == 0) {
        // fast path: 4 points = 12 floats = 3 x float4, contiguous 48 B
        const float4* k4 = (const float4*)k + (size_t)gid * 3;
        float4 p0 = k4[0];
        float4 p1 = k4[1];
        float4 p2 = k4[2];

        float n2[4];
        n2[0] = fmaf(p0.x, p0.x, fmaf(p0.y, p0.y, p0.z * p0.z));
        n2[1] = fmaf(p0.w, p0.w, fmaf(p1.x, p1.x, p1.y * p1.y));
        n2[2] = fmaf(p1.z, p1.z, fmaf(p1.w, p1.w, p2.x * p2.x));
        n2[3] = fmaf(p2.y, p2.y, fmaf(p2.z, p2.z, p2.w * p2.w));

        float4 o;
        float* op = &o.x;
#pragma unroll
        for (int j = 0; j < 4; ++j) {
            float t2 = L2 * n2[j];
            float tau = mann_tau(t2, L);
            op[j] = (t2 > 0.0f) ? g * tau : 0.0f;
        }
        *(float4*)(out + base) = o;
    } else {
        // tail (n not divisible by 4) — scalar fallback
        for (int j = 0; j < 4 && base + j < n; ++j) {
            const int i = base + j;
            float kx = k[3 * (size_t)i + 0];
            float ky = k[3 * (size_t)i + 1];
            float kz = k[3 * (size_t)i + 2];
            float t2 = L2 * (kx * kx + ky * ky + kz * kz);
            float tau = mann_tau(t2, L);
            out[i] = (t2 > 0.0f) ? g * tau : 0.0f;
        }
    }
}

extern "C" void kernel_launch(void* const* d_in, const int* in_sizes, int n_in,
                              void* d_out, int out_size, void* d_ws, size_t ws_size,
                              hipStream_t stream) {
    const float* k  = (const float*)d_in[0];
    const float* L  = (const float*)d_in[1];
    const float* g  = (const float*)d_in[2];
    float* out = (float*)d_out;

    const int n  = out_size;            // 256*256*128 = 8388608
    const int n4 = (n + 3) / 4;         // threads, 4 elements each
    const int block = 256;
    const int grid  = (n4 + block - 1) / block;

    mann_elt_kernel<<<grid, block, 0, stream>>>(k, L, g, out, n);
}